// Round 1
// 207.825 us; speedup vs baseline: 1.5535x; 1.5535x over previous
//
#include <hip/hip_runtime.h>

typedef short bfrag8 __attribute__((ext_vector_type(8)));
typedef float floatx4 __attribute__((ext_vector_type(4)));

#define MFMA_BF16(a, b, c) __builtin_amdgcn_mfma_f32_16x16x32_bf16((a), (b), (c), 0, 0, 0)

#define S_LEN 2048
#define D_MODEL 1024
#define NH 16
#define DK 64

__device__ __forceinline__ unsigned short f2bf(float f) {
  unsigned int u = __float_as_uint(f);
  u += 0x7fffu + ((u >> 16) & 1u);
  return (unsigned short)(u >> 16);
}

// ---------------- f32 -> bf16 conversion (vectorized) ----------------
__global__ __launch_bounds__(256) void cvt_f32_bf16(
    const float* __restrict__ in, unsigned short* __restrict__ out, int n) {
  int i = (blockIdx.x * 256 + threadIdx.x) * 4;
  if (i >= n) return;
  float4 v = *reinterpret_cast<const float4*>(in + i);
  uint2 p;
  p.x = (unsigned int)f2bf(v.x) | ((unsigned int)f2bf(v.y) << 16);
  p.y = (unsigned int)f2bf(v.z) | ((unsigned int)f2bf(v.w) << 16);
  *reinterpret_cast<uint2*>(out + i) = p;
}

// ---------------- NT GEMM: C[M,N] = A[M,K] * B[N,K]^T (+bias) ----------------
// M=4096, N=1024 (grid), K=1024. 128x128 tile, 4 waves, 64x64 per wave.
template <int WF32>
__global__ __launch_bounds__(256) void gemm_nt(
    const unsigned short* __restrict__ A, const unsigned short* __restrict__ Bw,
    unsigned short* __restrict__ Cb, float* __restrict__ Cf,
    const float* __restrict__ bias) {
  constexpr int K = 1024;
  constexpr int LDT = 40;  // 32 + 8 pad (keeps 16B align, spreads banks)
  __shared__ unsigned short As[128 * LDT];
  __shared__ unsigned short Bs[128 * LDT];
  const int tid = threadIdx.x, lane = tid & 63, wid = tid >> 6;
  const int lr = lane & 15, lk = lane >> 4;
  const int bm = blockIdx.y * 128, bn = blockIdx.x * 128;
  const int wm = (wid >> 1) * 64, wn = (wid & 1) * 64;
  floatx4 acc[4][4] = {};
  const int r0 = tid >> 2, kc = (tid & 3) * 8;
  const unsigned short* ga = A + (size_t)(bm + r0) * K + kc;
  const unsigned short* gb = Bw + (size_t)(bn + r0) * K + kc;

  for (int k0 = 0; k0 < K; k0 += 32) {
    __syncthreads();
    *reinterpret_cast<uint4*>(&As[r0 * LDT + kc]) =
        *reinterpret_cast<const uint4*>(ga + k0);
    *reinterpret_cast<uint4*>(&As[(r0 + 64) * LDT + kc]) =
        *reinterpret_cast<const uint4*>(ga + (size_t)64 * K + k0);
    *reinterpret_cast<uint4*>(&Bs[r0 * LDT + kc]) =
        *reinterpret_cast<const uint4*>(gb + k0);
    *reinterpret_cast<uint4*>(&Bs[(r0 + 64) * LDT + kc]) =
        *reinterpret_cast<const uint4*>(gb + (size_t)64 * K + k0);
    __syncthreads();
    bfrag8 af[4], bfr[4];
#pragma unroll
    for (int i = 0; i < 4; ++i)
      af[i] = *reinterpret_cast<const bfrag8*>(&As[(wm + i * 16 + lr) * LDT + lk * 8]);
#pragma unroll
    for (int j = 0; j < 4; ++j)
      bfr[j] = *reinterpret_cast<const bfrag8*>(&Bs[(wn + j * 16 + lr) * LDT + lk * 8]);
#pragma unroll
    for (int i = 0; i < 4; ++i)
#pragma unroll
      for (int j = 0; j < 4; ++j)
        acc[i][j] = MFMA_BF16(af[i], bfr[j], acc[i][j]);
  }

#pragma unroll
  for (int i = 0; i < 4; ++i)
#pragma unroll
    for (int j = 0; j < 4; ++j) {
      const int row = bm + wm + i * 16 + lk * 4;
      const int col = bn + wn + j * 16 + lr;
#pragma unroll
      for (int r = 0; r < 4; ++r) {
        if (WF32)
          Cf[(size_t)(row + r) * D_MODEL + col] = acc[i][j][r] + bias[col];
        else
          Cb[(size_t)(row + r) * D_MODEL + col] = f2bf(acc[i][j][r]);
      }
    }
}

// ---------------- transpose V: [B*S, D] -> Vt[bh][dk][S] ----------------
__global__ __launch_bounds__(256) void transpose_v(
    const unsigned short* __restrict__ V, unsigned short* __restrict__ Vt) {
  __shared__ unsigned short T[64 * 72];
  const int tid = threadIdx.x;
  const int bh = blockIdx.y, s0 = blockIdx.x * 64;
  const int b = bh >> 4, h = bh & 15;
  const unsigned short* src = V + ((size_t)(b * S_LEN + s0)) * D_MODEL + h * DK;
#pragma unroll
  for (int it = 0; it < 2; ++it) {
    int rr = it * 32 + (tid >> 3);
    int cc = (tid & 7) * 8;
    int sw = cc ^ (((rr >> 3) & 7) * 8);
    *reinterpret_cast<uint4*>(&T[rr * 72 + sw]) =
        *reinterpret_cast<const uint4*>(src + (size_t)rr * D_MODEL + cc);
  }
  __syncthreads();
#pragma unroll
  for (int it = 0; it < 2; ++it) {
    int chunk = it * 256 + tid;
    int d = chunk >> 3, sc = chunk & 7;
    unsigned short v[8];
#pragma unroll
    for (int i = 0; i < 8; ++i) {
      int row = sc * 8 + i;
      int col = ((d & ~7) ^ (((row >> 3) & 7) * 8)) + (d & 7);
      v[i] = T[row * 72 + col];
    }
    uint4 pk;
    pk.x = (unsigned int)v[0] | ((unsigned int)v[1] << 16);
    pk.y = (unsigned int)v[2] | ((unsigned int)v[3] << 16);
    pk.z = (unsigned int)v[4] | ((unsigned int)v[5] << 16);
    pk.w = (unsigned int)v[6] | ((unsigned int)v[7] << 16);
    *reinterpret_cast<uint4*>(&Vt[((size_t)bh * DK + d) * S_LEN + s0 + sc * 8]) = pk;
  }
}

// ---------------- fused relu-attention (transposed-score, P-in-wave) ----------
// Block: one (b,h), 64 q rows; 4 waves x 16 q rows each, full 64-k tile per wave.
// Scores computed transposed: S^T = mfma(A=K, B=Q^T)  -> lane holds q=lane&15,
// k = ni*16 + 4*lk + r. Mask load becomes one float4 per ni (4 consecutive k).
// P redistributed to PV B-fragment layout via a tiny wave-private LDS bounce
// (no __syncthreads). PV computed as O^T = mfma(A=V^T, B=P^T).
__global__ __launch_bounds__(256, 4) void attn_relu(
    const unsigned short* __restrict__ Q, const unsigned short* __restrict__ Kg,
    const unsigned short* __restrict__ Vt, const float* __restrict__ mask,
    unsigned short* __restrict__ O) {
  __shared__ __align__(16) unsigned short Kt[64 * 72];       // [k 64][d 64+8]
  __shared__ __align__(16) unsigned short Vl[64 * 72];       // [d 64][s 64+8]
  __shared__ __align__(16) unsigned short Pw[2 * 4 * 16 * 72];  // dbuf x wave x [q16][k64+8]
  const int tid = threadIdx.x, lane = tid & 63, wid = tid >> 6;
  const int lr = lane & 15, lk = lane >> 4;
  const int bh = blockIdx.y, q0 = blockIdx.x * 64;
  const int b = bh >> 4, h = bh & 15;
  const int q = q0 + wid * 16 + lr;  // this lane's q row (fragment column)

  // ---- Q B-fragments (loaded once, directly from global)
  const unsigned short* qptr = Q + (size_t)(b * S_LEN + q) * D_MODEL + h * DK;
  bfrag8 qf[2];
#pragma unroll
  for (int ks = 0; ks < 2; ++ks)
    qf[ks] = *reinterpret_cast<const bfrag8*>(qptr + ks * 32 + lk * 8);

  const unsigned short* kbase = Kg + (size_t)(b * S_LEN) * D_MODEL + h * DK;
  const unsigned short* vbase = Vt + (size_t)bh * DK * S_LEN;
  const float* mbase = mask + (size_t)q * S_LEN + lk * 4;

  const int srow = tid >> 3, scol = (tid & 7) * 8;  // staging: 8 threads/row

  floatx4 oacc[4] = {};

  for (int kt = 0; kt < S_LEN / 64; ++kt) {
    __syncthreads();  // previous-iteration LDS reads done
    // ---- stage K tile [64 k][64 d] and V^T tile [64 d][64 s]
#pragma unroll
    for (int it = 0; it < 2; ++it) {
      const int r = it * 32 + srow;
      *reinterpret_cast<uint4*>(&Kt[r * 72 + scol]) = *reinterpret_cast<const uint4*>(
          kbase + (size_t)(kt * 64 + r) * D_MODEL + scol);
      *reinterpret_cast<uint4*>(&Vl[r * 72 + scol]) = *reinterpret_cast<const uint4*>(
          vbase + (size_t)r * S_LEN + kt * 64 + scol);
    }
    __syncthreads();

    // ---- scores (transposed): sacc[ni] = S^T tile, rows k, cols q
    floatx4 sacc[4] = {};
#pragma unroll
    for (int ks = 0; ks < 2; ++ks) {
      bfrag8 kf[4];
#pragma unroll
      for (int ni = 0; ni < 4; ++ni)
        kf[ni] = *reinterpret_cast<const bfrag8*>(
            &Kt[(ni * 16 + lr) * 72 + ks * 32 + lk * 8]);
#pragma unroll
      for (int ni = 0; ni < 4; ++ni)
        sacc[ni] = MFMA_BF16(kf[ni], qf[ks], sacc[ni]);
    }

    // ---- epilogue: relu(scale*s + mask), pack bf16, wave-private P staging
    unsigned short* PwW = &Pw[((kt & 1) * 64 + wid * 16 + lr) * 72];
    const float* mrow = mbase + kt * 64;
#pragma unroll
    for (int ni = 0; ni < 4; ++ni) {
      float4 mv = *reinterpret_cast<const float4*>(mrow + ni * 16);
      float p0 = fmaxf(fmaf(sacc[ni][0], 0.125f, mv.x), 0.f);
      float p1 = fmaxf(fmaf(sacc[ni][1], 0.125f, mv.y), 0.f);
      float p2 = fmaxf(fmaf(sacc[ni][2], 0.125f, mv.z), 0.f);
      float p3 = fmaxf(fmaf(sacc[ni][3], 0.125f, mv.w), 0.f);
      uint2 pk;
      asm("v_cvt_pk_bf16_f32 %0, %1, %2" : "=v"(pk.x) : "v"(p0), "v"(p1));
      asm("v_cvt_pk_bf16_f32 %0, %1, %2" : "=v"(pk.y) : "v"(p2), "v"(p3));
      *reinterpret_cast<uint2*>(PwW + ni * 16 + lk * 4) = pk;
    }
    // wave-internal visibility (no cross-wave sharing of Pw)
    asm volatile("s_waitcnt lgkmcnt(0)" ::: "memory");

    // ---- PV: O^T = mfma(A = V^T frag, B = P^T frag)
#pragma unroll
    for (int kk = 0; kk < 2; ++kk) {
      bfrag8 pB = *reinterpret_cast<const bfrag8*>(PwW + kk * 32 + lk * 8);
#pragma unroll
      for (int dj = 0; dj < 4; ++dj) {
        bfrag8 vb = *reinterpret_cast<const bfrag8*>(
            &Vl[(dj * 16 + lr) * 72 + kk * 32 + lk * 8]);
        oacc[dj] = MFMA_BF16(vb, pB, oacc[dj]);
      }
    }
  }

  // ---- write O (bf16, [B*S][D]); O^T frag: row d = dj*16+4*lk+r, col q
  const size_t orow = (size_t)(b * S_LEN + q) * D_MODEL + h * DK + lk * 4;
#pragma unroll
  for (int dj = 0; dj < 4; ++dj) {
    uint2 pk;
    pk.x = (unsigned int)f2bf(oacc[dj][0]) | ((unsigned int)f2bf(oacc[dj][1]) << 16);
    pk.y = (unsigned int)f2bf(oacc[dj][2]) | ((unsigned int)f2bf(oacc[dj][3]) << 16);
    *reinterpret_cast<uint2*>(&O[orow + dj * 16]) = pk;
  }
}

extern "C" void kernel_launch(void* const* d_in, const int* in_sizes, int n_in,
                              void* d_out, int out_size, void* d_ws, size_t ws_size,
                              hipStream_t stream) {
  const float* x = (const float*)d_in[0];
  const float* mask = (const float*)d_in[1];
  const float* Wq = (const float*)d_in[2];
  const float* Wk = (const float*)d_in[3];
  const float* Wv = (const float*)d_in[4];
  const float* Wfc = (const float*)d_in[5];
  const float* bfc = (const float*)d_in[6];
  float* out = (float*)d_out;

  char* ws = (char*)d_ws;
  const size_t MB = 1u << 20;
  unsigned short* xb = (unsigned short*)(ws + 0 * MB);    // 8 MB
  unsigned short* Wqb = (unsigned short*)(ws + 8 * MB);   // 2 MB
  unsigned short* Wkb = (unsigned short*)(ws + 10 * MB);  // 2 MB
  unsigned short* Wvb = (unsigned short*)(ws + 12 * MB);  // 2 MB
  unsigned short* Wfb = (unsigned short*)(ws + 14 * MB);  // 2 MB
  unsigned short* Qw = (unsigned short*)(ws + 16 * MB);   // 8 MB
  unsigned short* Kw = (unsigned short*)(ws + 24 * MB);   // 8 MB
  unsigned short* Vw = (unsigned short*)(ws + 32 * MB);   // 8 MB
  unsigned short* Vtw = (unsigned short*)(ws + 40 * MB);  // 8 MB
  unsigned short* Ow = (unsigned short*)(ws + 48 * MB);   // 8 MB

  const int nx = 2 * S_LEN * D_MODEL;      // 4194304
  const int nw = D_MODEL * D_MODEL;        // 1048576
  cvt_f32_bf16<<<nx / 1024, 256, 0, stream>>>(x, xb, nx);
  cvt_f32_bf16<<<nw / 1024, 256, 0, stream>>>(Wq, Wqb, nw);
  cvt_f32_bf16<<<nw / 1024, 256, 0, stream>>>(Wk, Wkb, nw);
  cvt_f32_bf16<<<nw / 1024, 256, 0, stream>>>(Wv, Wvb, nw);
  cvt_f32_bf16<<<nw / 1024, 256, 0, stream>>>(Wfc, Wfb, nw);

  dim3 gg(D_MODEL / 128, (2 * S_LEN) / 128);  // (8, 32)
  gemm_nt<0><<<gg, 256, 0, stream>>>(xb, Wqb, Qw, nullptr, nullptr);
  gemm_nt<0><<<gg, 256, 0, stream>>>(xb, Wkb, Kw, nullptr, nullptr);
  gemm_nt<0><<<gg, 256, 0, stream>>>(xb, Wvb, Vw, nullptr, nullptr);

  transpose_v<<<dim3(S_LEN / 64, 32), 256, 0, stream>>>(Vw, Vtw);

  attn_relu<<<dim3(S_LEN / 64, 32), 256, 0, stream>>>(Qw, Kw, Vtw, mask, Ow);

  gemm_nt<1><<<gg, 256, 0, stream>>>(Ow, Wfb, nullptr, out, bfc);
}

// Round 2
// 151.087 us; speedup vs baseline: 2.1369x; 1.3755x over previous
//
#include <hip/hip_runtime.h>

typedef short bfrag8 __attribute__((ext_vector_type(8)));
typedef float floatx4 __attribute__((ext_vector_type(4)));

#define MFMA_BF16(a, b, c) __builtin_amdgcn_mfma_f32_16x16x32_bf16((a), (b), (c), 0, 0, 0)

#define S_LEN 2048
#define D_MODEL 1024
#define NH 16
#define DK 64

__device__ __forceinline__ unsigned short f2bf(float f) {
  unsigned int u = __float_as_uint(f);
  u += 0x7fffu + ((u >> 16) & 1u);
  return (unsigned short)(u >> 16);
}

typedef const __attribute__((address_space(1))) unsigned int guint;
typedef __attribute__((address_space(3))) unsigned int luint;
__device__ __forceinline__ void gload16(const void* g, void* l) {
  __builtin_amdgcn_global_load_lds((guint*)g, (luint*)l, 16, 0, 0);
}

// ---------------- all f32 -> bf16 conversions in ONE launch ----------------
// regions (in 1024-elt blocks): x 4096 | mask 4096 | wq wk wv wfc 1024 each
__global__ __launch_bounds__(256) void cvt_all(
    const float* __restrict__ x, const float* __restrict__ mask,
    const float* __restrict__ wq, const float* __restrict__ wk,
    const float* __restrict__ wv, const float* __restrict__ wfc,
    unsigned short* __restrict__ xb, unsigned short* __restrict__ maskb,
    unsigned short* __restrict__ wqb, unsigned short* __restrict__ wkb,
    unsigned short* __restrict__ wvb, unsigned short* __restrict__ wfb) {
  const int bid = blockIdx.x;
  const float* src;
  unsigned short* dst;
  int base;
  if (bid < 4096) { src = x; dst = xb; base = bid; }
  else if (bid < 8192) { src = mask; dst = maskb; base = bid - 4096; }
  else if (bid < 9216) { src = wq; dst = wqb; base = bid - 8192; }
  else if (bid < 10240) { src = wk; dst = wkb; base = bid - 9216; }
  else if (bid < 11264) { src = wv; dst = wvb; base = bid - 10240; }
  else { src = wfc; dst = wfb; base = bid - 11264; }
  const int i = (base * 256 + threadIdx.x) * 4;
  float4 v = *reinterpret_cast<const float4*>(src + i);
  uint2 p;
  p.x = (unsigned int)f2bf(v.x) | ((unsigned int)f2bf(v.y) << 16);
  p.y = (unsigned int)f2bf(v.z) | ((unsigned int)f2bf(v.w) << 16);
  *reinterpret_cast<uint2*>(dst + i) = p;
}

// ---------------- NT GEMM: C[M,N] = A[M,K] * B[N,K]^T (+bias) ----------------
// 128 x TN tile, 4 waves. 2-phase pipelined global_load_lds staging,
// linear LDS (64B rows) + XOR swizzle (((row>>1)&3)<<4) via pre-swizzled source.
// z-grid selects among up to 3 B/C pairs (merged QKV launch).
template <int WF32, int TN>
__global__ __launch_bounds__(256) void gemm_nt(
    const unsigned short* __restrict__ A, const unsigned short* __restrict__ B0,
    const unsigned short* __restrict__ B1, const unsigned short* __restrict__ B2,
    unsigned short* __restrict__ C0, unsigned short* __restrict__ C1,
    unsigned short* __restrict__ C2, float* __restrict__ Cf,
    const float* __restrict__ bias) {
  constexpr int K = 1024;
  constexpr int NJ = TN / 32;  // per-wave N fragments
  __shared__ unsigned short As[2][128 * 32];
  __shared__ unsigned short Bs[2][TN * 32];
  const int z = blockIdx.z;
  const unsigned short* Bw = (z == 0) ? B0 : (z == 1) ? B1 : B2;
  unsigned short* Cb = (z == 0) ? C0 : (z == 1) ? C1 : C2;
  const int tid = threadIdx.x, lane = tid & 63, wid = tid >> 6;
  const int lr = lane & 15, lk = lane >> 4;
  const int bm = blockIdx.y * 128, bn = blockIdx.x * TN;
  const int wm = (wid >> 1) * 64, wn = (wid & 1) * (TN / 2);
  floatx4 acc[4][NJ] = {};

  // staging geometry: thread t handles LDS row srow = t>>2, 16B chunk (t&3)
  const int srow = tid >> 2, scb = (tid & 3) * 16;
  const int ssw = scb ^ (((srow >> 1) & 3) << 4);  // pre-swizzled source col
  const char* gA = (const char*)A + ((size_t)(bm + srow) * K) * 2 + ssw;
  const char* gB = (const char*)Bw + ((size_t)(bn + srow) * K) * 2 + ssw;

  auto stage = [&](int buf, int k0) {
    gload16(gA + (size_t)k0 * 2, (char*)&As[buf][0] + tid * 16);
    gload16(gA + ((size_t)64 * K + k0) * 2, (char*)&As[buf][0] + 4096 + tid * 16);
    gload16(gB + (size_t)k0 * 2, (char*)&Bs[buf][0] + tid * 16);
    if constexpr (TN == 128)
      gload16(gB + ((size_t)64 * K + k0) * 2, (char*)&Bs[buf][0] + 4096 + tid * 16);
  };

  stage(0, 0);
  __syncthreads();  // drains vmcnt(0)
  int cur = 0;
  const int csw = (lk * 16) ^ (((lr >> 1) & 3) << 4);  // read-side swizzle
  for (int k0 = 0; k0 < K; k0 += 32) {
    if (k0 + 32 < K) stage(cur ^ 1, k0 + 32);
    const char* Ab = (const char*)&As[cur][0];
    const char* Bb = (const char*)&Bs[cur][0];
    bfrag8 af[4], bfr[NJ];
#pragma unroll
    for (int i = 0; i < 4; ++i)
      af[i] = *reinterpret_cast<const bfrag8*>(Ab + (wm + i * 16 + lr) * 64 + csw);
#pragma unroll
    for (int j = 0; j < NJ; ++j)
      bfr[j] = *reinterpret_cast<const bfrag8*>(Bb + (wn + j * 16 + lr) * 64 + csw);
#pragma unroll
    for (int i = 0; i < 4; ++i)
#pragma unroll
      for (int j = 0; j < NJ; ++j)
        acc[i][j] = MFMA_BF16(af[i], bfr[j], acc[i][j]);
    __syncthreads();  // prefetch landed + everyone done reading cur
    cur ^= 1;
  }

#pragma unroll
  for (int i = 0; i < 4; ++i)
#pragma unroll
    for (int j = 0; j < NJ; ++j) {
      const int row = bm + wm + i * 16 + lk * 4;
      const int col = bn + wn + j * 16 + lr;
#pragma unroll
      for (int r = 0; r < 4; ++r) {
        if (WF32)
          Cf[(size_t)(row + r) * D_MODEL + col] = acc[i][j][r] + bias[col];
        else
          Cb[(size_t)(row + r) * D_MODEL + col] = f2bf(acc[i][j][r]);
      }
    }
}

// ---------------- transpose V: [B*S, D] -> Vt[bh][dk][S] ----------------
__global__ __launch_bounds__(256) void transpose_v(
    const unsigned short* __restrict__ V, unsigned short* __restrict__ Vt) {
  __shared__ unsigned short T[64 * 72];
  const int tid = threadIdx.x;
  const int bh = blockIdx.y, s0 = blockIdx.x * 64;
  const int b = bh >> 4, h = bh & 15;
  const unsigned short* src = V + ((size_t)(b * S_LEN + s0)) * D_MODEL + h * DK;
#pragma unroll
  for (int it = 0; it < 2; ++it) {
    int rr = it * 32 + (tid >> 3);
    int cc = (tid & 7) * 8;
    int sw = cc ^ (((rr >> 3) & 7) * 8);
    *reinterpret_cast<uint4*>(&T[rr * 72 + sw]) =
        *reinterpret_cast<const uint4*>(src + (size_t)rr * D_MODEL + cc);
  }
  __syncthreads();
#pragma unroll
  for (int it = 0; it < 2; ++it) {
    int chunk = it * 256 + tid;
    int d = chunk >> 3, sc = chunk & 7;
    unsigned short v[8];
#pragma unroll
    for (int i = 0; i < 8; ++i) {
      int row = sc * 8 + i;
      int col = ((d & ~7) ^ (((row >> 3) & 7) * 8)) + (d & 7);
      v[i] = T[row * 72 + col];
    }
    uint4 pk;
    pk.x = (unsigned int)v[0] | ((unsigned int)v[1] << 16);
    pk.y = (unsigned int)v[2] | ((unsigned int)v[3] << 16);
    pk.z = (unsigned int)v[4] | ((unsigned int)v[5] << 16);
    pk.w = (unsigned int)v[6] | ((unsigned int)v[7] << 16);
    *reinterpret_cast<uint4*>(&Vt[((size_t)bh * DK + d) * S_LEN + s0 + sc * 8]) = pk;
  }
}

// ---------------- fused relu-attention (transposed-score, 2-phase pipelined) --
// Block: one (b,h), 64 q rows; 4 waves x 16 q. K/V tiles double-buffered,
// staged via global_load_lds (linear 128B rows, XOR swizzle (row&7)<<4 through
// pre-swizzled source). Prefetch kt+1 before computing kt; single barrier/iter.
// P stays wave-private in a single-buffered swizzled LDS strip. bf16 mask.
__global__ __launch_bounds__(256, 4) void attn_relu(
    const unsigned short* __restrict__ Q, const unsigned short* __restrict__ Kg,
    const unsigned short* __restrict__ Vt, const unsigned short* __restrict__ Mb,
    unsigned short* __restrict__ O) {
  __shared__ unsigned short Kt[2][64 * 64];  // [k][d] 16 KB
  __shared__ unsigned short Vl[2][64 * 64];  // [d][s] 16 KB
  __shared__ unsigned short Pw[4][16 * 64];  // per-wave [q16][k64] 8 KB
  const int tid = threadIdx.x, lane = tid & 63, wid = tid >> 6;
  const int lr = lane & 15, lk = lane >> 4;
  // XCD-aware swizzle over 1024 blocks (32 q-tiles x 32 bh): each XCD gets
  // 128 consecutive flats = 4 bh -> K/V/mask L2 locality. 1024 % 8 == 0.
  int flat = blockIdx.y * 32 + blockIdx.x;
  flat = (flat & 7) * 128 + (flat >> 3);
  const int bh = flat >> 5, q0 = (flat & 31) * 64;
  const int b = bh >> 4, h = bh & 15;
  const int q = q0 + wid * 16 + lr;

  // Q B-fragments straight from global
  const unsigned short* qptr = Q + (size_t)(b * S_LEN + q) * D_MODEL + h * DK;
  bfrag8 qf[2];
#pragma unroll
  for (int ks = 0; ks < 2; ++ks)
    qf[ks] = *reinterpret_cast<const bfrag8*>(qptr + ks * 32 + lk * 8);

  // staging: thread t -> LDS row p*32 + (t>>3), 16B chunk (t&7); source pre-swz
  const int srow = tid >> 3, scb = (tid & 7) * 16;
  const int ssw = scb ^ ((srow & 7) << 4);
  const char* kg = (const char*)Kg + ((size_t)(b * S_LEN + srow)) * 2048 + h * 128 + ssw;
  const char* vg = (const char*)Vt + (size_t)bh * (DK * S_LEN * 2) +
                   (size_t)srow * (S_LEN * 2) + ssw;
  const unsigned short* mrow = Mb + (size_t)q * S_LEN + lk * 4;

  floatx4 oacc[4] = {};

  // prologue: stage tile 0
#pragma unroll
  for (int p = 0; p < 2; ++p) {
    gload16(kg + (size_t)(p * 32) * 2048, (char*)&Kt[0][0] + p * 4096 + tid * 16);
    gload16(vg + (size_t)(p * 32) * 4096, (char*)&Vl[0][0] + p * 4096 + tid * 16);
  }
  __syncthreads();

  int cur = 0;
  const int swzq = (lr & 7) << 4;
  char* PwW = (char*)&Pw[wid][0] + lr * 128;
  for (int kt = 0; kt < S_LEN / 64; ++kt) {
    // prefetch next K/V tile into the other buffer (lands by end-of-iter barrier)
    if (kt + 1 < S_LEN / 64) {
#pragma unroll
      for (int p = 0; p < 2; ++p) {
        gload16(kg + ((size_t)(kt + 1) * 64 + p * 32) * 2048,
                (char*)&Kt[cur ^ 1][0] + p * 4096 + tid * 16);
        gload16(vg + (size_t)(p * 32) * 4096 + (size_t)(kt + 1) * 128,
                (char*)&Vl[cur ^ 1][0] + p * 4096 + tid * 16);
      }
    }

    // ---- scores (transposed): sacc[ni] rows k, cols q
    floatx4 sacc[4] = {};
    __builtin_amdgcn_s_setprio(1);
#pragma unroll
    for (int ks = 0; ks < 2; ++ks) {
      bfrag8 kf[4];
#pragma unroll
      for (int ni = 0; ni < 4; ++ni)
        kf[ni] = *reinterpret_cast<const bfrag8*>(
            (const char*)&Kt[cur][0] + (ni * 16 + lr) * 128 + ((ks * 64 + lk * 16) ^ swzq));
#pragma unroll
      for (int ni = 0; ni < 4; ++ni)
        sacc[ni] = MFMA_BF16(kf[ni], qf[ks], sacc[ni]);
    }
    __builtin_amdgcn_s_setprio(0);

    // ---- relu(scale*s + mask) -> bf16 -> wave-private swizzled P strip
#pragma unroll
    for (int ni = 0; ni < 4; ++ni) {
      uint2 mv = *reinterpret_cast<const uint2*>(mrow + kt * 64 + ni * 16);
      float m0 = __uint_as_float((mv.x & 0xffffu) << 16);
      float m1 = __uint_as_float(mv.x & 0xffff0000u);
      float m2 = __uint_as_float((mv.y & 0xffffu) << 16);
      float m3 = __uint_as_float(mv.y & 0xffff0000u);
      float p0 = fmaxf(fmaf(sacc[ni][0], 0.125f, m0), 0.f);
      float p1 = fmaxf(fmaf(sacc[ni][1], 0.125f, m1), 0.f);
      float p2 = fmaxf(fmaf(sacc[ni][2], 0.125f, m2), 0.f);
      float p3 = fmaxf(fmaf(sacc[ni][3], 0.125f, m3), 0.f);
      uint2 pk;
      asm("v_cvt_pk_bf16_f32 %0, %1, %2" : "=v"(pk.x) : "v"(p0), "v"(p1));
      asm("v_cvt_pk_bf16_f32 %0, %1, %2" : "=v"(pk.y) : "v"(p2), "v"(p3));
      *reinterpret_cast<uint2*>(PwW + ((ni * 32 + lk * 8) ^ swzq)) = pk;
    }
    asm volatile("s_waitcnt lgkmcnt(0)" ::: "memory");

    // ---- PV: O^T += mfma(A = V^T frag, B = P^T frag)
    __builtin_amdgcn_s_setprio(1);
#pragma unroll
    for (int kk = 0; kk < 2; ++kk) {
      const int cV = (kk * 64 + lk * 16) ^ swzq;
      bfrag8 pB = *reinterpret_cast<const bfrag8*>(PwW + cV);
#pragma unroll
      for (int dj = 0; dj < 4; ++dj) {
        bfrag8 vb = *reinterpret_cast<const bfrag8*>(
            (const char*)&Vl[cur][0] + (dj * 16 + lr) * 128 + cV);
        oacc[dj] = MFMA_BF16(vb, pB, oacc[dj]);
      }
    }
    __builtin_amdgcn_s_setprio(0);
    __syncthreads();  // prefetch visible; all waves done with cur
    cur ^= 1;
  }

  // ---- write O (bf16, [B*S][D]); O^T frag: row d = dj*16+4*lk+r, col q
  const size_t orow = (size_t)(b * S_LEN + q) * D_MODEL + h * DK + lk * 4;
#pragma unroll
  for (int dj = 0; dj < 4; ++dj) {
    uint2 pk;
    pk.x = (unsigned int)f2bf(oacc[dj][0]) | ((unsigned int)f2bf(oacc[dj][1]) << 16);
    pk.y = (unsigned int)f2bf(oacc[dj][2]) | ((unsigned int)f2bf(oacc[dj][3]) << 16);
    *reinterpret_cast<uint2*>(&O[orow + dj * 16]) = pk;
  }
}

extern "C" void kernel_launch(void* const* d_in, const int* in_sizes, int n_in,
                              void* d_out, int out_size, void* d_ws, size_t ws_size,
                              hipStream_t stream) {
  const float* x = (const float*)d_in[0];
  const float* mask = (const float*)d_in[1];
  const float* Wq = (const float*)d_in[2];
  const float* Wk = (const float*)d_in[3];
  const float* Wv = (const float*)d_in[4];
  const float* Wfc = (const float*)d_in[5];
  const float* bfc = (const float*)d_in[6];
  float* out = (float*)d_out;

  char* ws = (char*)d_ws;
  const size_t MB = 1u << 20;
  unsigned short* xb = (unsigned short*)(ws + 0 * MB);     // 8 MB (reused as Ow)
  unsigned short* Wqb = (unsigned short*)(ws + 8 * MB);    // 2 MB
  unsigned short* Wkb = (unsigned short*)(ws + 10 * MB);   // 2 MB
  unsigned short* Wvb = (unsigned short*)(ws + 12 * MB);   // 2 MB
  unsigned short* Wfb = (unsigned short*)(ws + 14 * MB);   // 2 MB
  unsigned short* Qw = (unsigned short*)(ws + 16 * MB);    // 8 MB
  unsigned short* Kw = (unsigned short*)(ws + 24 * MB);    // 8 MB
  unsigned short* Vw = (unsigned short*)(ws + 32 * MB);    // 8 MB
  unsigned short* Vtw = (unsigned short*)(ws + 40 * MB);   // 8 MB
  unsigned short* maskb = (unsigned short*)(ws + 48 * MB); // 8 MB
  unsigned short* Ow = xb;  // attn runs after QKV GEMMs; xb is dead by then

  cvt_all<<<12288, 256, 0, stream>>>(x, mask, Wq, Wk, Wv, Wfc,
                                     xb, maskb, Wqb, Wkb, Wvb, Wfb);

  // merged Q/K/V projection: one launch, z selects weight/output
  gemm_nt<0, 128><<<dim3(D_MODEL / 128, (2 * S_LEN) / 128, 3), 256, 0, stream>>>(
      xb, Wqb, Wkb, Wvb, Qw, Kw, Vw, nullptr, nullptr);

  transpose_v<<<dim3(S_LEN / 64, 32), 256, 0, stream>>>(Vw, Vtw);

  attn_relu<<<dim3(S_LEN / 64, 32), 256, 0, stream>>>(Qw, Kw, Vtw, maskb, Ow);

  // FC: 128x64 tiles -> 512 blocks (2/CU) for latency hiding
  gemm_nt<1, 64><<<dim3(D_MODEL / 64, (2 * S_LEN) / 128, 1), 256, 0, stream>>>(
      Ow, Wfb, nullptr, nullptr, nullptr, nullptr, nullptr, out, bfc);
}